// Round 9
// baseline (583.791 us; speedup 1.0000x reference)
//
#include <hip/hip_runtime.h>
#include <math.h>

// Problem constants
#define M_ 16
#define N_ 4096
#define D_ 128
#define P_ 8192
#define H_ 32

// Projection tiling
#define NIC 32
#define ICH (N_/NIC)
#define NCB 16            // 256-column blocks, 1 col/thread

// Attention chunking
#define CHUNK 128
#define NCH (P_/CHUNK)    // 64 cache chunks
#define NCH1 (NCH+1)      // +1 for the 16 appended rows

// Workspace layout (float offsets)
#define QKV_SZ    (3*H_*M_*D_)
#define PART_OFF  (QKV_SZ)
#define OPART_OFF (QKV_SZ)
#define OPART_SZ  (H_*NCH1*M_*D_)
#define ML_OFF    (OPART_OFF + OPART_SZ)

// ---------------------------------------------------------------------------
// Kernel 1: partial QKV projection. grid (NCB, NIC, 3), block 256. (as r7)
// ---------------------------------------------------------------------------
__global__ __launch_bounds__(256) void k_proj(const float* __restrict__ X,
                                              const float* __restrict__ Wq,
                                              const float* __restrict__ Wk,
                                              const float* __restrict__ Wv,
                                              float* __restrict__ part) {
  const int mat = blockIdx.z;
  const float* __restrict__ W = (mat == 0) ? Wq : ((mat == 1) ? Wk : Wv);
  const int cb = blockIdx.x, ic = blockIdx.y;
  const int t = threadIdx.x;
  const int j0 = cb * 256 + t;
  const int i0 = ic * ICH;

  __shared__ __align__(16) float XT[ICH][20];

  {
    const int i_l = t & 127, mh = t >> 7;
#pragma unroll
    for (int r = 0; r < 8; ++r)
      XT[i_l][mh * 8 + r] = X[(size_t)(mh * 8 + r) * N_ + i0 + i_l];
  }
  __syncthreads();

  float acc[16];
#pragma unroll
  for (int m = 0; m < 16; ++m) acc[m] = 0.f;

#pragma unroll 8
  for (int i = 0; i < ICH; ++i) {
    const float wv = __builtin_nontemporal_load(W + (size_t)(i0 + i) * N_ + j0);
    float xr[16];
    {
      float4 xv;
      xv = *reinterpret_cast<const float4*>(&XT[i][0]);
      xr[0] = xv.x; xr[1] = xv.y; xr[2] = xv.z; xr[3] = xv.w;
      xv = *reinterpret_cast<const float4*>(&XT[i][4]);
      xr[4] = xv.x; xr[5] = xv.y; xr[6] = xv.z; xr[7] = xv.w;
      xv = *reinterpret_cast<const float4*>(&XT[i][8]);
      xr[8] = xv.x; xr[9] = xv.y; xr[10] = xv.z; xr[11] = xv.w;
      xv = *reinterpret_cast<const float4*>(&XT[i][12]);
      xr[12] = xv.x; xr[13] = xv.y; xr[14] = xv.z; xr[15] = xv.w;
    }
#pragma unroll
    for (int m = 0; m < 16; ++m) acc[m] = fmaf(xr[m], wv, acc[m]);
  }

#pragma unroll
  for (int m = 0; m < 16; ++m)
    __builtin_nontemporal_store(acc[m], part + (size_t)((mat * NIC + ic) * M_ + m) * N_ + j0);
}

// ---------------------------------------------------------------------------
// Kernel 2: reduce partials, RMS-norm q/k, relayout. (as r7)
// ---------------------------------------------------------------------------
__global__ __launch_bounds__(256) void k_reduce(const float* __restrict__ part,
                                                float* __restrict__ qkv) {
  const int mat = blockIdx.z, m = blockIdx.y, nc = blockIdx.x;
  const int t = threadIdx.x;
  const int n = nc * 256 + t;

  float s = 0.f;
#pragma unroll
  for (int ic = 0; ic < NIC; ++ic)
    s += __builtin_nontemporal_load(part + (size_t)((mat * NIC + ic) * M_ + m) * N_ + n);

  float ss = s * s;
#pragma unroll
  for (int off = 1; off < 64; off <<= 1) ss += __shfl_xor(ss, off);
  __shared__ float wsum[4];
  const int wave = t >> 6, lane = t & 63;
  if (lane == 0) wsum[wave] = ss;
  __syncthreads();
  const int half = t >> 7;
  const float tot = wsum[half * 2] + wsum[half * 2 + 1];
  const float scale = (mat < 2) ? rsqrtf(tot * (1.0f / 128.0f)) : 1.0f;

  const int h = n >> 7, d = n & 127;
  qkv[(size_t)((mat * H_ + h) * M_ + m) * D_ + d] = s * scale;
}

// ---------------------------------------------------------------------------
// fold-reduce 16 values over the 8 dq-lanes (lane bits 0..2).
// Result: lane dq holds S[2*dq] in a[0], S[2*dq+1] in a[1], where
// S[v] = sum over the 8 dq lanes of a_dq[v].
// ---------------------------------------------------------------------------
__device__ __forceinline__ void fold16(float a[16], int dq) {
#pragma unroll
  for (int i = 0; i < 8; ++i) {
    const bool hi = (dq & 4) != 0;
    const float send = hi ? a[i] : a[i + 8];
    const float recv = __shfl_xor(send, 4);
    a[i] = (hi ? a[i + 8] : a[i]) + recv;
  }
#pragma unroll
  for (int i = 0; i < 4; ++i) {
    const bool hi = (dq & 2) != 0;
    const float send = hi ? a[i] : a[i + 4];
    const float recv = __shfl_xor(send, 2);
    a[i] = (hi ? a[i + 4] : a[i]) + recv;
  }
#pragma unroll
  for (int i = 0; i < 2; ++i) {
    const bool hi = (dq & 1) != 0;
    const float send = hi ? a[i] : a[i + 2];
    const float recv = __shfl_xor(send, 1);
    a[i] = (hi ? a[i + 2] : a[i]) + recv;
  }
}

// ---------------------------------------------------------------------------
// Kernel 3: p-split streaming attention. grid (NCH1, H_), block 256 = 4 waves.
// K/V are loaded ONCE per block: wave w owns disjoint rows [32w, 32w+32) of
// the 128-row chunk and computes partial (m,l,O) for ALL 16 m over its rows.
// (r7's m-split had every wave streaming the full chunk -> 4x L2/VMEM
// traffic; FETCH_SIZE hid it because L2 dedup'd the HBM side.)
// Per 8-row subtile: K 4xdwordx4 (lane=(pg,dq)), V 8xfloat2 (lane=dl),
// scores a[16] fold-reduced over dq lanes, softmax weights/factors through
// wave-private wx/fx strips. No barriers in the loop; 2 barriers at the end
// merge the 4 wave-partials through obuf (aliases the dead q tile).
// ---------------------------------------------------------------------------
__global__ __launch_bounds__(256, 2) void k_attn(const float* __restrict__ cacheK,
                                                 const float* __restrict__ cacheV,
                                                 const float* __restrict__ qkv,
                                                 float* __restrict__ opart,
                                                 float* __restrict__ ml) {
  const int c = blockIdx.x, h = blockIdx.y;
  const int t = threadIdx.x;
  const int wave = t >> 6, lane = t & 63;
  const int valid = (c < NCH) ? CHUNK : M_;
  const float* __restrict__ Ksrc = (c < NCH)
      ? (cacheK + ((size_t)h * P_ + (size_t)c * CHUNK) * D_)
      : (qkv + (size_t)((1 * H_ + h) * M_) * D_);
  const float* __restrict__ Vsrc = (c < NCH)
      ? (cacheV + ((size_t)h * P_ + (size_t)c * CHUNK) * D_)
      : (qkv + (size_t)((2 * H_ + h) * M_) * D_);

  // smem0: q tile (8 KB) during main loop; o-merge buffer (32 KB) after.
  __shared__ __align__(16) float smem0[4 * M_ * D_];   // 32 KB
  __shared__ __align__(16) float wx[4][8][16];          // 2 KB  w[row][m]
  __shared__ __align__(16) float fx[4][16];             // rescale per m
  __shared__ __align__(16) float mlx[4][16][2];         // per-wave m,l

  float* qs = smem0;

  // stage q (16x128)
  {
    const float4* src = reinterpret_cast<const float4*>(qkv + (size_t)(h * M_) * D_);
    float4* dst = reinterpret_cast<float4*>(qs);
    dst[t] = src[t];
    dst[t + 256] = src[t + 256];
  }
  __syncthreads();

  const int pg = lane >> 3, dq = lane & 7;  // scores: 8 rows x 8 d-groups
  const int dl = lane * 2;                  // PV: d-pair per lane

  // wave's row range
  const int rbase = wave * 32;
  const int rcount = (valid > rbase) ? ((valid - rbase < 32) ? valid - rbase : 32) : 0;
  const int nsub = rcount >> 3;

  float mrun0 = -3.0e38f, mrun1 = -3.0e38f;
  float lrun0 = 0.f, lrun1 = 0.f;
  float2 o[16];
#pragma unroll
  for (int mi = 0; mi < 16; ++mi) o[mi] = make_float2(0.f, 0.f);

  if (nsub > 0) {
    // initial K prefetch: kk[dd] = K[rbase+pg][dq*4 + dd*32 ..+4)
    float4 kk[4];
#pragma unroll
    for (int dd = 0; dd < 4; ++dd)
      kk[dd] = *reinterpret_cast<const float4*>(
          Ksrc + (size_t)(rbase + pg) * D_ + dd * 32 + dq * 4);

#pragma unroll 1
    for (int s = 0; s < nsub; ++s) {
      const int r0 = rbase + s * 8;

      // ---- issue V rows (outstanding through scores+softmax) ----
      float2 vv[8];
#pragma unroll
      for (int j = 0; j < 8; ++j)
        vv[j] = *reinterpret_cast<const float2*>(Vsrc + (size_t)(r0 + j) * D_ + dl);

      // ---- scores: a[mi] = q[mi] . K[r0+pg] (dq-slice) ----
      float a[16];
#pragma unroll
      for (int mi = 0; mi < 16; ++mi) a[mi] = 0.f;
#pragma unroll
      for (int dd = 0; dd < 4; ++dd) {
        const float4 kv = kk[dd];
#pragma unroll
        for (int mi = 0; mi < 16; ++mi) {
          const float4 q4 = *reinterpret_cast<const float4*>(&qs[mi * D_ + dd * 32 + dq * 4]);
          a[mi] = fmaf(q4.x, kv.x, a[mi]);
          a[mi] = fmaf(q4.y, kv.y, a[mi]);
          a[mi] = fmaf(q4.z, kv.z, a[mi]);
          a[mi] = fmaf(q4.w, kv.w, a[mi]);
        }
      }

      // ---- prefetch K for next subtile (phantom clamp on last) ----
      {
        int rn = r0 + 8 + pg;
        rn = (rn < valid) ? rn : (valid - 1);
#pragma unroll
        for (int dd = 0; dd < 4; ++dd)
          kk[dd] = *reinterpret_cast<const float4*>(
              Ksrc + (size_t)rn * D_ + dd * 32 + dq * 4);
      }

      // ---- fold d-split: lane dq ends with S[m=2dq], S[m=2dq+1] ----
      fold16(a, dq);
      const float s0 = a[0], s1 = a[1];

      // ---- online softmax (row dim = pg lanes, bits 3..5) ----
      float t0 = s0, t1 = s1;
      t0 = fmaxf(t0, __shfl_xor(t0, 8));
      t0 = fmaxf(t0, __shfl_xor(t0, 16));
      t0 = fmaxf(t0, __shfl_xor(t0, 32));
      t1 = fmaxf(t1, __shfl_xor(t1, 8));
      t1 = fmaxf(t1, __shfl_xor(t1, 16));
      t1 = fmaxf(t1, __shfl_xor(t1, 32));
      const float mn0 = fmaxf(mrun0, t0), mn1 = fmaxf(mrun1, t1);
      const float fc0 = __expf(mrun0 - mn0), fc1 = __expf(mrun1 - mn1);
      mrun0 = mn0; mrun1 = mn1;
      const float w0 = __expf(s0 - mn0), w1 = __expf(s1 - mn1);
      float rs0 = w0, rs1 = w1;
      rs0 += __shfl_xor(rs0, 8); rs0 += __shfl_xor(rs0, 16); rs0 += __shfl_xor(rs0, 32);
      rs1 += __shfl_xor(rs1, 8); rs1 += __shfl_xor(rs1, 16); rs1 += __shfl_xor(rs1, 32);
      lrun0 = lrun0 * fc0 + rs0;
      lrun1 = lrun1 * fc1 + rs1;

      // publish weights + factors (wave-private strips; no barrier needed)
      *reinterpret_cast<float2*>(&wx[wave][pg][2 * dq]) = make_float2(w0, w1);
      if (pg == 0)
        *reinterpret_cast<float2*>(&fx[wave][2 * dq]) = make_float2(fc0, fc1);

      // ---- rescale o by fx[m] ----
      {
        const float4* fxv = reinterpret_cast<const float4*>(&fx[wave][0]);
        const float4 f0 = fxv[0], f1 = fxv[1], f2 = fxv[2], f3 = fxv[3];
#define RSC(i, ff) o[i].x *= ff; o[i].y *= ff;
        RSC(0, f0.x) RSC(1, f0.y) RSC(2, f0.z) RSC(3, f0.w)
        RSC(4, f1.x) RSC(5, f1.y) RSC(6, f1.z) RSC(7, f1.w)
        RSC(8, f2.x) RSC(9, f2.y) RSC(10, f2.z) RSC(11, f2.w)
        RSC(12, f3.x) RSC(13, f3.y) RSC(14, f3.z) RSC(15, f3.w)
#undef RSC
      }

      // ---- PV: all 16 m, this wave's 8 rows ----
#pragma unroll
      for (int j = 0; j < 8; ++j) {
        const float4* wv = reinterpret_cast<const float4*>(&wx[wave][j][0]);
        const float4 wA = wv[0], wB = wv[1], wC = wv[2], wD = wv[3];
        const float2 v = vv[j];
#define PVM(i, wc) o[i].x = fmaf(wc, v.x, o[i].x); o[i].y = fmaf(wc, v.y, o[i].y);
        PVM(0, wA.x) PVM(1, wA.y) PVM(2, wA.z) PVM(3, wA.w)
        PVM(4, wB.x) PVM(5, wB.y) PVM(6, wB.z) PVM(7, wB.w)
        PVM(8, wC.x) PVM(9, wC.y) PVM(10, wC.z) PVM(11, wC.w)
        PVM(12, wD.x) PVM(13, wD.y) PVM(14, wD.z) PVM(15, wD.w)
#undef PVM
      }
    }
  }

  // ---- merge the 4 wave-partials ----
  __syncthreads();  // all waves done with qs/wx; safe to overwrite smem0
  float* obuf = smem0;  // [4][16][128]
#pragma unroll
  for (int mi = 0; mi < 16; ++mi)
    *reinterpret_cast<float2*>(&obuf[wave * 2048 + mi * 128 + dl]) = o[mi];
  if (lane < 8) {
    mlx[wave][2 * lane + 0][0] = mrun0; mlx[wave][2 * lane + 0][1] = lrun0;
    mlx[wave][2 * lane + 1][0] = mrun1; mlx[wave][2 * lane + 1][1] = lrun1;
  }
  __syncthreads();

  {
    const int mm = t >> 4, seg = t & 15;  // 16 m x 16 segs of 8 d
    const float m0v = mlx[0][mm][0], m1v = mlx[1][mm][0];
    const float m2v = mlx[2][mm][0], m3v = mlx[3][mm][0];
    const float mstar = fmaxf(fmaxf(m0v, m1v), fmaxf(m2v, m3v));
    float ew[4];
    ew[0] = __expf(m0v - mstar);
    ew[1] = __expf(m1v - mstar);
    ew[2] = __expf(m2v - mstar);
    ew[3] = __expf(m3v - mstar);
    const float T = mlx[0][mm][1] * ew[0] + mlx[1][mm][1] * ew[1] +
                    mlx[2][mm][1] * ew[2] + mlx[3][mm][1] * ew[3];
    float4 acc0 = make_float4(0.f, 0.f, 0.f, 0.f);
    float4 acc1 = make_float4(0.f, 0.f, 0.f, 0.f);
#pragma unroll
    for (int w2 = 0; w2 < 4; ++w2) {
      const float ee = ew[w2];
      const float4 v0 = *reinterpret_cast<const float4*>(&obuf[w2 * 2048 + mm * 128 + seg * 8]);
      const float4 v1 = *reinterpret_cast<const float4*>(&obuf[w2 * 2048 + mm * 128 + seg * 8 + 4]);
      acc0.x = fmaf(ee, v0.x, acc0.x); acc0.y = fmaf(ee, v0.y, acc0.y);
      acc0.z = fmaf(ee, v0.z, acc0.z); acc0.w = fmaf(ee, v0.w, acc0.w);
      acc1.x = fmaf(ee, v1.x, acc1.x); acc1.y = fmaf(ee, v1.y, acc1.y);
      acc1.z = fmaf(ee, v1.z, acc1.z); acc1.w = fmaf(ee, v1.w, acc1.w);
    }
    const size_t base = (size_t)((h * NCH1 + c) * M_) * D_;
    *reinterpret_cast<float4*>(opart + base + (size_t)mm * D_ + seg * 8) = acc0;
    *reinterpret_cast<float4*>(opart + base + (size_t)mm * D_ + seg * 8 + 4) = acc1;
    if (seg == 0) {
      ml[((size_t)(h * NCH1 + c) * M_ + mm) * 2 + 0] = mstar;
      ml[((size_t)(h * NCH1 + c) * M_ + mm) * 2 + 1] = T;
    }
  }
}

// ---------------------------------------------------------------------------
// Kernel 4: combine 65 chunk partials per (h, m). grid (M_, H_), block 128.
// ---------------------------------------------------------------------------
__global__ __launch_bounds__(128) void k_comb(const float* __restrict__ opart,
                                              const float* __restrict__ ml,
                                              float* __restrict__ out) {
  const int m = blockIdx.x, h = blockIdx.y, t = threadIdx.x;
  __shared__ float Ms[NCH1], Ls[NCH1];
  if (t < NCH1) {
    Ms[t] = ml[((size_t)(h * NCH1 + t) * M_ + m) * 2 + 0];
    Ls[t] = ml[((size_t)(h * NCH1 + t) * M_ + m) * 2 + 1];
  }
  __syncthreads();
  float gM = -3.0e38f;
#pragma unroll
  for (int c2 = 0; c2 < NCH1; ++c2) gM = fmaxf(gM, Ms[c2]);

  const float* __restrict__ ob = opart + (size_t)h * NCH1 * M_ * D_ + (size_t)m * D_ + t;
  float T = 0.f, o0 = 0.f, o1 = 0.f, o2 = 0.f, o3 = 0.f;
#pragma unroll 4
  for (int c2 = 0; c2 < NCH1 - 1; c2 += 4) {
    const float f0 = __expf(Ms[c2 + 0] - gM);
    const float f1 = __expf(Ms[c2 + 1] - gM);
    const float f2 = __expf(Ms[c2 + 2] - gM);
    const float f3 = __expf(Ms[c2 + 3] - gM);
    T = fmaf(Ls[c2 + 0], f0, T); T = fmaf(Ls[c2 + 1], f1, T);
    T = fmaf(Ls[c2 + 2], f2, T); T = fmaf(Ls[c2 + 3], f3, T);
    o0 = fmaf(ob[(size_t)(c2 + 0) * M_ * D_], f0, o0);
    o1 = fmaf(ob[(size_t)(c2 + 1) * M_ * D_], f1, o1);
    o2 = fmaf(ob[(size_t)(c2 + 2) * M_ * D_], f2, o2);
    o3 = fmaf(ob[(size_t)(c2 + 3) * M_ * D_], f3, o3);
  }
  {
    const int c2 = NCH1 - 1;
    const float f = __expf(Ms[c2] - gM);
    T = fmaf(Ls[c2], f, T);
    o0 = fmaf(ob[(size_t)c2 * M_ * D_], f, o0);
  }
  out[(size_t)m * N_ + h * D_ + t] = (o0 + o1 + o2 + o3) / T;
}

// ---------------------------------------------------------------------------
extern "C" void kernel_launch(void* const* d_in, const int* in_sizes, int n_in,
                              void* d_out, int out_size, void* d_ws, size_t ws_size,
                              hipStream_t stream) {
  const float* X  = (const float*)d_in[0];
  const float* Wq = (const float*)d_in[1];
  const float* Wk = (const float*)d_in[2];
  const float* Wv = (const float*)d_in[3];
  const float* cK = (const float*)d_in[4];
  const float* cV = (const float*)d_in[5];
  float* ws    = (float*)d_ws;
  float* qkv   = ws;
  float* part  = ws + PART_OFF;
  float* opart = ws + OPART_OFF;
  float* mlbuf = ws + ML_OFF;
  float* out   = (float*)d_out;

  hipLaunchKernelGGL(k_proj,   dim3(NCB, NIC, 3), dim3(256), 0, stream, X, Wq, Wk, Wv, part);
  hipLaunchKernelGGL(k_reduce, dim3(16, M_, 3),   dim3(256), 0, stream, part, qkv);
  hipLaunchKernelGGL(k_attn,   dim3(NCH1, H_),    dim3(256), 0, stream, cK, cV, qkv, opart, mlbuf);
  hipLaunchKernelGGL(k_comb,   dim3(M_, H_),      dim3(128), 0, stream, opart, mlbuf, out);
}

// Round 10
// 192.317 us; speedup vs baseline: 3.0356x; 3.0356x over previous
//
#include <hip/hip_runtime.h>
#include <math.h>

// Problem constants
#define M_ 16
#define N_ 4096
#define D_ 128
#define P_ 8192
#define H_ 32

// Projection tiling
#define NIC 32
#define ICH (N_/NIC)
#define NCB 16            // 256-column blocks, 1 col/thread

// Attention chunking
#define CHUNK 128
#define NCH (P_/CHUNK)    // 64 cache chunks
#define NCH1 (NCH+1)      // +1 for the 16 appended rows

// Workspace layout (float offsets)
#define QKV_SZ    (3*H_*M_*D_)
#define PART_OFF  (QKV_SZ)
#define OPART_OFF (QKV_SZ)
#define OPART_SZ  (H_*NCH1*M_*D_)
#define ML_OFF    (OPART_OFF + OPART_SZ)

// ---------------------------------------------------------------------------
// Kernel 1: partial QKV projection. grid (NCB, NIC, 3), block 256. (as r7)
// ---------------------------------------------------------------------------
__global__ __launch_bounds__(256) void k_proj(const float* __restrict__ X,
                                              const float* __restrict__ Wq,
                                              const float* __restrict__ Wk,
                                              const float* __restrict__ Wv,
                                              float* __restrict__ part) {
  const int mat = blockIdx.z;
  const float* __restrict__ W = (mat == 0) ? Wq : ((mat == 1) ? Wk : Wv);
  const int cb = blockIdx.x, ic = blockIdx.y;
  const int t = threadIdx.x;
  const int j0 = cb * 256 + t;
  const int i0 = ic * ICH;

  __shared__ __align__(16) float XT[ICH][20];

  {
    const int i_l = t & 127, mh = t >> 7;
#pragma unroll
    for (int r = 0; r < 8; ++r)
      XT[i_l][mh * 8 + r] = X[(size_t)(mh * 8 + r) * N_ + i0 + i_l];
  }
  __syncthreads();

  float acc[16];
#pragma unroll
  for (int m = 0; m < 16; ++m) acc[m] = 0.f;

#pragma unroll 8
  for (int i = 0; i < ICH; ++i) {
    const float wv = __builtin_nontemporal_load(W + (size_t)(i0 + i) * N_ + j0);
    float xr[16];
    {
      float4 xv;
      xv = *reinterpret_cast<const float4*>(&XT[i][0]);
      xr[0] = xv.x; xr[1] = xv.y; xr[2] = xv.z; xr[3] = xv.w;
      xv = *reinterpret_cast<const float4*>(&XT[i][4]);
      xr[4] = xv.x; xr[5] = xv.y; xr[6] = xv.z; xr[7] = xv.w;
      xv = *reinterpret_cast<const float4*>(&XT[i][8]);
      xr[8] = xv.x; xr[9] = xv.y; xr[10] = xv.z; xr[11] = xv.w;
      xv = *reinterpret_cast<const float4*>(&XT[i][12]);
      xr[12] = xv.x; xr[13] = xv.y; xr[14] = xv.z; xr[15] = xv.w;
    }
#pragma unroll
    for (int m = 0; m < 16; ++m) acc[m] = fmaf(xr[m], wv, acc[m]);
  }

#pragma unroll
  for (int m = 0; m < 16; ++m)
    __builtin_nontemporal_store(acc[m], part + (size_t)((mat * NIC + ic) * M_ + m) * N_ + j0);
}

// ---------------------------------------------------------------------------
// Kernel 2: reduce partials, RMS-norm q/k, relayout. (as r7)
// ---------------------------------------------------------------------------
__global__ __launch_bounds__(256) void k_reduce(const float* __restrict__ part,
                                                float* __restrict__ qkv) {
  const int mat = blockIdx.z, m = blockIdx.y, nc = blockIdx.x;
  const int t = threadIdx.x;
  const int n = nc * 256 + t;

  float s = 0.f;
#pragma unroll
  for (int ic = 0; ic < NIC; ++ic)
    s += __builtin_nontemporal_load(part + (size_t)((mat * NIC + ic) * M_ + m) * N_ + n);

  float ss = s * s;
#pragma unroll
  for (int off = 1; off < 64; off <<= 1) ss += __shfl_xor(ss, off);
  __shared__ float wsum[4];
  const int wave = t >> 6, lane = t & 63;
  if (lane == 0) wsum[wave] = ss;
  __syncthreads();
  const int half = t >> 7;
  const float tot = wsum[half * 2] + wsum[half * 2 + 1];
  const float scale = (mat < 2) ? rsqrtf(tot * (1.0f / 128.0f)) : 1.0f;

  const int h = n >> 7, d = n & 127;
  qkv[(size_t)((mat * H_ + h) * M_ + m) * D_ + d] = s * scale;
}

// ---------------------------------------------------------------------------
// fold8: reduce a[0..7] over the 8 dq-lanes (lane bits 0..2).
// Returns the fully-summed S[m_local=dq] on lane dq.
// ---------------------------------------------------------------------------
__device__ __forceinline__ float fold8(float a[8], int dq) {
#pragma unroll
  for (int i = 0; i < 4; ++i) {
    const float send = (dq & 4) ? a[i] : a[i + 4];
    const float recv = __shfl_xor(send, 4);
    a[i] = ((dq & 4) ? a[i + 4] : a[i]) + recv;
  }
#pragma unroll
  for (int i = 0; i < 2; ++i) {
    const float send = (dq & 2) ? a[i] : a[i + 2];
    const float recv = __shfl_xor(send, 2);
    a[i] = ((dq & 2) ? a[i + 2] : a[i]) + recv;
  }
  {
    const float send = (dq & 1) ? a[0] : a[1];
    const float recv = __shfl_xor(send, 1);
    a[0] = ((dq & 1) ? a[1] : a[0]) + recv;
  }
  return a[0];
}

// q[mbase+mi] . K-slice: 4 float4 of q (stride 32 floats) against kk[0..3]
__device__ __forceinline__ float dot16(const float* __restrict__ qrow,
                                       const float4 k0, const float4 k1,
                                       const float4 k2, const float4 k3) {
  const float4 q0 = *reinterpret_cast<const float4*>(qrow);
  const float4 q1 = *reinterpret_cast<const float4*>(qrow + 32);
  const float4 q2 = *reinterpret_cast<const float4*>(qrow + 64);
  const float4 q3 = *reinterpret_cast<const float4*>(qrow + 96);
  float s;
  s = q0.x * k0.x;
  s = fmaf(q0.y, k0.y, s); s = fmaf(q0.z, k0.z, s); s = fmaf(q0.w, k0.w, s);
  s = fmaf(q1.x, k1.x, s); s = fmaf(q1.y, k1.y, s);
  s = fmaf(q1.z, k1.z, s); s = fmaf(q1.w, k1.w, s);
  s = fmaf(q2.x, k2.x, s); s = fmaf(q2.y, k2.y, s);
  s = fmaf(q2.z, k2.z, s); s = fmaf(q2.w, k2.w, s);
  s = fmaf(q3.x, k3.x, s); s = fmaf(q3.y, k3.y, s);
  s = fmaf(q3.z, k3.z, s); s = fmaf(q3.w, k3.w, s);
  return s;
}

// ---------------------------------------------------------------------------
// Kernel 3: p-split attention, register-disciplined. grid (NCH1, H_),
// block 512 = 8 waves = 4 row-groups x 2 m-halves. Each K/V row is loaded by
// exactly ONE wave (r7's m-split had 4x CU-side L2 traffic). Wave owns rows
// [rg*32, rg*32+32) and m [mh*8, mh*8+8). Per 16-row batch:
//   K loads (8 dwordx4 up-front) -> scores rows 0-7 -> rows 8-15
//   (sched_barrier(0) per mi caps the q ds_read cluster at 4 -> no r9 spill)
//   fold8 -> 1 score/lane -> pg-shfl softmax (1 exp/lane) -> wx strip
//   V loads (16 dwordx2 up-front) -> PV via wx broadcast reads.
// No barriers in the loop; 2 syncthreads + LDS merge at the end
// (obuf aliases the dead q/wx region; LDS total 33 KB -> 4 blocks/CU).
// ---------------------------------------------------------------------------
__global__ __launch_bounds__(512, 4) void k_attn(const float* __restrict__ cacheK,
                                                 const float* __restrict__ cacheV,
                                                 const float* __restrict__ qkv,
                                                 float* __restrict__ opart,
                                                 float* __restrict__ ml) {
  const int c = blockIdx.x, h = blockIdx.y;
  const int t = threadIdx.x;
  const int wave = t >> 6, lane = t & 63;
  const int valid = (c < NCH) ? CHUNK : M_;
  const float* __restrict__ Ksrc = (c < NCH)
      ? (cacheK + ((size_t)h * P_ + (size_t)c * CHUNK) * D_)
      : (qkv + (size_t)((1 * H_ + h) * M_) * D_);
  const float* __restrict__ Vsrc = (c < NCH)
      ? (cacheV + ((size_t)h * P_ + (size_t)c * CHUNK) * D_)
      : (qkv + (size_t)((2 * H_ + h) * M_) * D_);

  __shared__ __align__(16) float smem[8192];     // 32 KB: qs[2048] + wx[1024] / obuf[8192]
  __shared__ __align__(16) float mlx[8][8][2];   // per-wave (m, l)

  float* qs = smem;                        // [16][128]
  float* wxp = smem + 2048 + wave * 128;   // wave-private [16 rows][8 m]

  // stage q (16x128) — the only barrier-producing stage before the merge
  {
    const float4* src = reinterpret_cast<const float4*>(qkv + (size_t)(h * M_) * D_);
    reinterpret_cast<float4*>(qs)[t] = src[t];
  }
  __syncthreads();

  const int pg = lane >> 3, dq = lane & 7;
  const int dl = lane * 2;
  const int rg = wave >> 1, mbase = (wave & 1) * 8;
  const int rbase = rg * 32;
  int rc = valid - rbase; rc = (rc < 0) ? 0 : ((rc > 32) ? 32 : rc);
  const int nb = rc >> 4;   // 16-row batches: 2, 1, or 0

  float mrun = -3.0e38f, lrun = 0.f;
  float2 o[8];
#pragma unroll
  for (int mi = 0; mi < 8; ++mi) o[mi] = make_float2(0.f, 0.f);

#pragma unroll 1
  for (int b = 0; b < nb; ++b) {
    const int r0 = rbase + b * 16;

    // ---- K loads for both 8-row halves, issued up-front ----
    float4 kA0, kA1, kA2, kA3, kB0, kB1, kB2, kB3;
    {
      const float* ka = Ksrc + (size_t)(r0 + pg) * D_ + dq * 4;
      kA0 = *reinterpret_cast<const float4*>(ka);
      kA1 = *reinterpret_cast<const float4*>(ka + 32);
      kA2 = *reinterpret_cast<const float4*>(ka + 64);
      kA3 = *reinterpret_cast<const float4*>(ka + 96);
      const float* kb = Ksrc + (size_t)(r0 + 8 + pg) * D_ + dq * 4;
      kB0 = *reinterpret_cast<const float4*>(kb);
      kB1 = *reinterpret_cast<const float4*>(kb + 32);
      kB2 = *reinterpret_cast<const float4*>(kb + 64);
      kB3 = *reinterpret_cast<const float4*>(kb + 96);
    }

    // ---- scores rows r0..r0+7 ----
    float a[8];
#pragma unroll
    for (int mi = 0; mi < 8; ++mi) {
      a[mi] = dot16(qs + (mbase + mi) * D_ + dq * 4, kA0, kA1, kA2, kA3);
      __builtin_amdgcn_sched_barrier(0);  // cap q ds_read clustering (r9 spill fix)
    }
    const float sA = fold8(a, dq);

    // ---- scores rows r0+8..r0+15 ----
#pragma unroll
    for (int mi = 0; mi < 8; ++mi) {
      a[mi] = dot16(qs + (mbase + mi) * D_ + dq * 4, kB0, kB1, kB2, kB3);
      __builtin_amdgcn_sched_barrier(0);
    }
    const float sB = fold8(a, dq);

    // ---- online softmax over the 16 rows (rows live across pg lanes) ----
    float tmax = fmaxf(sA, sB);
    tmax = fmaxf(tmax, __shfl_xor(tmax, 8));
    tmax = fmaxf(tmax, __shfl_xor(tmax, 16));
    tmax = fmaxf(tmax, __shfl_xor(tmax, 32));
    const float mnew = fmaxf(mrun, tmax);
    const float fc = __expf(mrun - mnew);
    mrun = mnew;
    const float wA = __expf(sA - mnew);
    const float wB = __expf(sB - mnew);
    float rs = wA + wB;
    rs += __shfl_xor(rs, 8); rs += __shfl_xor(rs, 16); rs += __shfl_xor(rs, 32);
    lrun = lrun * fc + rs;

    // publish weights (wave-private strip; same-wave RAW ordered by lgkmcnt)
    wxp[pg * 8 + dq] = wA;
    wxp[(8 + pg) * 8 + dq] = wB;

    // ---- rescale o by this batch's factor (per-m fc gathered via shfl) ----
#pragma unroll
    for (int mi = 0; mi < 8; ++mi) {
      const float fcm = __shfl(fc, (lane & 56) | mi);
      o[mi].x *= fcm; o[mi].y *= fcm;
    }

    // ---- V loads for all 16 rows, issued up-front ----
    float2 vvA[8], vvB[8];
#pragma unroll
    for (int j = 0; j < 8; ++j)
      vvA[j] = *reinterpret_cast<const float2*>(Vsrc + (size_t)(r0 + j) * D_ + dl);
#pragma unroll
    for (int j = 0; j < 8; ++j)
      vvB[j] = *reinterpret_cast<const float2*>(Vsrc + (size_t)(r0 + 8 + j) * D_ + dl);

    // ---- PV rows r0..r0+7 ----
#pragma unroll
    for (int j = 0; j < 8; ++j) {
      const float4 w0 = *reinterpret_cast<const float4*>(&wxp[j * 8]);
      const float4 w1 = *reinterpret_cast<const float4*>(&wxp[j * 8 + 4]);
      const float2 v = vvA[j];
#define PVM(i, wc) o[i].x = fmaf(wc, v.x, o[i].x); o[i].y = fmaf(wc, v.y, o[i].y);
      PVM(0, w0.x) PVM(1, w0.y) PVM(2, w0.z) PVM(3, w0.w)
      PVM(4, w1.x) PVM(5, w1.y) PVM(6, w1.z) PVM(7, w1.w)
#undef PVM
      if (j & 1) __builtin_amdgcn_sched_barrier(0);
    }
    // ---- PV rows r0+8..r0+15 ----
#pragma unroll
    for (int j = 0; j < 8; ++j) {
      const float4 w0 = *reinterpret_cast<const float4*>(&wxp[(8 + j) * 8]);
      const float4 w1 = *reinterpret_cast<const float4*>(&wxp[(8 + j) * 8 + 4]);
      const float2 v = vvB[j];
#define PVM(i, wc) o[i].x = fmaf(wc, v.x, o[i].x); o[i].y = fmaf(wc, v.y, o[i].y);
      PVM(0, w0.x) PVM(1, w0.y) PVM(2, w0.z) PVM(3, w0.w)
      PVM(4, w1.x) PVM(5, w1.y) PVM(6, w1.z) PVM(7, w1.w)
#undef PVM
      if (j & 1) __builtin_amdgcn_sched_barrier(0);
    }
  }

  // ---- merge the 8 wave-partials (obuf aliases dead qs/wx) ----
  __syncthreads();
  float* obuf = smem;  // [8 waves][8 m][128 d]
#pragma unroll
  for (int mi = 0; mi < 8; ++mi)
    *reinterpret_cast<float2*>(&obuf[wave * 1024 + mi * 128 + dl]) = o[mi];
  if (lane < 8) { mlx[wave][lane][0] = mrun; mlx[wave][lane][1] = lrun; }
  __syncthreads();

  {
    const int mm = t >> 5, seg = t & 31;    // 16 m x 32 segments of 4 d
    const int w0i = mm >> 3, mi = mm & 7;   // wave = rg*2 + w0i holds this m
    float mv[4], lv[4];
#pragma unroll
    for (int r = 0; r < 4; ++r) { mv[r] = mlx[r * 2 + w0i][mi][0]; lv[r] = mlx[r * 2 + w0i][mi][1]; }
    const float mstar = fmaxf(fmaxf(mv[0], mv[1]), fmaxf(mv[2], mv[3]));
    float ew[4];
    float T = 0.f;
#pragma unroll
    for (int r = 0; r < 4; ++r) { ew[r] = __expf(mv[r] - mstar); T = fmaf(lv[r], ew[r], T); }
    float4 acc = make_float4(0.f, 0.f, 0.f, 0.f);
#pragma unroll
    for (int r = 0; r < 4; ++r) {
      const float4 v = *reinterpret_cast<const float4*>(&obuf[(r * 2 + w0i) * 1024 + mi * 128 + seg * 4]);
      acc.x = fmaf(ew[r], v.x, acc.x); acc.y = fmaf(ew[r], v.y, acc.y);
      acc.z = fmaf(ew[r], v.z, acc.z); acc.w = fmaf(ew[r], v.w, acc.w);
    }
    const size_t base = (size_t)((h * NCH1 + c) * M_ + mm) * D_;
    *reinterpret_cast<float4*>(opart + base + seg * 4) = acc;
    if (seg == 0) {
      ml[((size_t)(h * NCH1 + c) * M_ + mm) * 2 + 0] = mstar;
      ml[((size_t)(h * NCH1 + c) * M_ + mm) * 2 + 1] = T;
    }
  }
}

// ---------------------------------------------------------------------------
// Kernel 4: combine 65 chunk partials per (h, m). grid (M_, H_), block 128.
// ---------------------------------------------------------------------------
__global__ __launch_bounds__(128) void k_comb(const float* __restrict__ opart,
                                              const float* __restrict__ ml,
                                              float* __restrict__ out) {
  const int m = blockIdx.x, h = blockIdx.y, t = threadIdx.x;
  __shared__ float Ms[NCH1], Ls[NCH1];
  if (t < NCH1) {
    Ms[t] = ml[((size_t)(h * NCH1 + t) * M_ + m) * 2 + 0];
    Ls[t] = ml[((size_t)(h * NCH1 + t) * M_ + m) * 2 + 1];
  }
  __syncthreads();
  float gM = -3.0e38f;
#pragma unroll
  for (int c2 = 0; c2 < NCH1; ++c2) gM = fmaxf(gM, Ms[c2]);

  const float* __restrict__ ob = opart + (size_t)h * NCH1 * M_ * D_ + (size_t)m * D_ + t;
  float T = 0.f, o0 = 0.f, o1 = 0.f, o2 = 0.f, o3 = 0.f;
#pragma unroll 4
  for (int c2 = 0; c2 < NCH1 - 1; c2 += 4) {
    const float f0 = __expf(Ms[c2 + 0] - gM);
    const float f1 = __expf(Ms[c2 + 1] - gM);
    const float f2 = __expf(Ms[c2 + 2] - gM);
    const float f3 = __expf(Ms[c2 + 3] - gM);
    T = fmaf(Ls[c2 + 0], f0, T); T = fmaf(Ls[c2 + 1], f1, T);
    T = fmaf(Ls[c2 + 2], f2, T); T = fmaf(Ls[c2 + 3], f3, T);
    o0 = fmaf(ob[(size_t)(c2 + 0) * M_ * D_], f0, o0);
    o1 = fmaf(ob[(size_t)(c2 + 1) * M_ * D_], f1, o1);
    o2 = fmaf(ob[(size_t)(c2 + 2) * M_ * D_], f2, o2);
    o3 = fmaf(ob[(size_t)(c2 + 3) * M_ * D_], f3, o3);
  }
  {
    const int c2 = NCH1 - 1;
    const float f = __expf(Ms[c2] - gM);
    T = fmaf(Ls[c2], f, T);
    o0 = fmaf(ob[(size_t)c2 * M_ * D_], f, o0);
  }
  out[(size_t)m * N_ + h * D_ + t] = (o0 + o1 + o2 + o3) / T;
}

// ---------------------------------------------------------------------------
extern "C" void kernel_launch(void* const* d_in, const int* in_sizes, int n_in,
                              void* d_out, int out_size, void* d_ws, size_t ws_size,
                              hipStream_t stream) {
  const float* X  = (const float*)d_in[0];
  const float* Wq = (const float*)d_in[1];
  const float* Wk = (const float*)d_in[2];
  const float* Wv = (const float*)d_in[3];
  const float* cK = (const float*)d_in[4];
  const float* cV = (const float*)d_in[5];
  float* ws    = (float*)d_ws;
  float* qkv   = ws;
  float* part  = ws + PART_OFF;
  float* opart = ws + OPART_OFF;
  float* mlbuf = ws + ML_OFF;
  float* out   = (float*)d_out;

  hipLaunchKernelGGL(k_proj,   dim3(NCB, NIC, 3), dim3(256), 0, stream, X, Wq, Wk, Wv, part);
  hipLaunchKernelGGL(k_reduce, dim3(16, M_, 3),   dim3(256), 0, stream, part, qkv);
  hipLaunchKernelGGL(k_attn,   dim3(NCH1, H_),    dim3(512), 0, stream, cK, cV, qkv, opart, mlbuf);
  hipLaunchKernelGGL(k_comb,   dim3(M_, H_),      dim3(128), 0, stream, opart, mlbuf, out);
}

// Round 11
// 135.892 us; speedup vs baseline: 4.2960x; 1.4152x over previous
//
#include <hip/hip_runtime.h>
#include <math.h>

// Problem constants
#define M_ 16
#define N_ 4096
#define D_ 128
#define P_ 8192
#define H_ 32

// Projection tiling
#define NIC 32
#define ICH (N_/NIC)
#define NCB 16            // 256-column blocks, 1 col/thread

// Attention chunking
#define CHUNK 128
#define NCH (P_/CHUNK)    // 64 cache chunks
#define NCH1 (NCH+1)      // +1 for the 16 appended rows

// Workspace layout (float offsets)
#define QKV_SZ    (3*H_*M_*D_)
#define PART_OFF  (QKV_SZ)
#define OPART_OFF (QKV_SZ)
#define OPART_SZ  (H_*NCH1*M_*D_)
#define ML_OFF    (OPART_OFF + OPART_SZ)

// ---------------------------------------------------------------------------
// Kernel 1: partial QKV projection. grid (NCB, NIC, 3), block 256. (as r7)
// ---------------------------------------------------------------------------
__global__ __launch_bounds__(256) void k_proj(const float* __restrict__ X,
                                              const float* __restrict__ Wq,
                                              const float* __restrict__ Wk,
                                              const float* __restrict__ Wv,
                                              float* __restrict__ part) {
  const int mat = blockIdx.z;
  const float* __restrict__ W = (mat == 0) ? Wq : ((mat == 1) ? Wk : Wv);
  const int cb = blockIdx.x, ic = blockIdx.y;
  const int t = threadIdx.x;
  const int j0 = cb * 256 + t;
  const int i0 = ic * ICH;

  __shared__ __align__(16) float XT[ICH][20];

  {
    const int i_l = t & 127, mh = t >> 7;
#pragma unroll
    for (int r = 0; r < 8; ++r)
      XT[i_l][mh * 8 + r] = X[(size_t)(mh * 8 + r) * N_ + i0 + i_l];
  }
  __syncthreads();

  float acc[16];
#pragma unroll
  for (int m = 0; m < 16; ++m) acc[m] = 0.f;

#pragma unroll 8
  for (int i = 0; i < ICH; ++i) {
    const float wv = __builtin_nontemporal_load(W + (size_t)(i0 + i) * N_ + j0);
    float xr[16];
    {
      float4 xv;
      xv = *reinterpret_cast<const float4*>(&XT[i][0]);
      xr[0] = xv.x; xr[1] = xv.y; xr[2] = xv.z; xr[3] = xv.w;
      xv = *reinterpret_cast<const float4*>(&XT[i][4]);
      xr[4] = xv.x; xr[5] = xv.y; xr[6] = xv.z; xr[7] = xv.w;
      xv = *reinterpret_cast<const float4*>(&XT[i][8]);
      xr[8] = xv.x; xr[9] = xv.y; xr[10] = xv.z; xr[11] = xv.w;
      xv = *reinterpret_cast<const float4*>(&XT[i][12]);
      xr[12] = xv.x; xr[13] = xv.y; xr[14] = xv.z; xr[15] = xv.w;
    }
#pragma unroll
    for (int m = 0; m < 16; ++m) acc[m] = fmaf(xr[m], wv, acc[m]);
  }

#pragma unroll
  for (int m = 0; m < 16; ++m)
    __builtin_nontemporal_store(acc[m], part + (size_t)((mat * NIC + ic) * M_ + m) * N_ + j0);
}

// ---------------------------------------------------------------------------
// Kernel 2: reduce partials, RMS-norm q/k, relayout. (as r7)
// ---------------------------------------------------------------------------
__global__ __launch_bounds__(256) void k_reduce(const float* __restrict__ part,
                                                float* __restrict__ qkv) {
  const int mat = blockIdx.z, m = blockIdx.y, nc = blockIdx.x;
  const int t = threadIdx.x;
  const int n = nc * 256 + t;

  float s = 0.f;
#pragma unroll
  for (int ic = 0; ic < NIC; ++ic)
    s += __builtin_nontemporal_load(part + (size_t)((mat * NIC + ic) * M_ + m) * N_ + n);

  float ss = s * s;
#pragma unroll
  for (int off = 1; off < 64; off <<= 1) ss += __shfl_xor(ss, off);
  __shared__ float wsum[4];
  const int wave = t >> 6, lane = t & 63;
  if (lane == 0) wsum[wave] = ss;
  __syncthreads();
  const int half = t >> 7;
  const float tot = wsum[half * 2] + wsum[half * 2 + 1];
  const float scale = (mat < 2) ? rsqrtf(tot * (1.0f / 128.0f)) : 1.0f;

  const int h = n >> 7, d = n & 127;
  qkv[(size_t)((mat * H_ + h) * M_ + m) * D_ + d] = s * scale;
}

// ---------------------------------------------------------------------------
// fold8: reduce a[0..7] over the 8 dq-lanes (lane bits 0..2).
// Returns the fully-summed S[m_local=dq] on lane dq.
// ---------------------------------------------------------------------------
__device__ __forceinline__ float fold8(float a[8], int dq) {
#pragma unroll
  for (int i = 0; i < 4; ++i) {
    const float send = (dq & 4) ? a[i] : a[i + 4];
    const float recv = __shfl_xor(send, 4);
    a[i] = ((dq & 4) ? a[i + 4] : a[i]) + recv;
  }
#pragma unroll
  for (int i = 0; i < 2; ++i) {
    const float send = (dq & 2) ? a[i] : a[i + 2];
    const float recv = __shfl_xor(send, 2);
    a[i] = ((dq & 2) ? a[i + 2] : a[i]) + recv;
  }
  {
    const float send = (dq & 1) ? a[0] : a[1];
    const float recv = __shfl_xor(send, 1);
    a[0] = ((dq & 1) ? a[1] : a[0]) + recv;
  }
  return a[0];
}

// q[mbase+mi] . K-slice: 4 float4 of q (stride 32 floats) against kk[0..3]
__device__ __forceinline__ float dot16(const float* __restrict__ qrow,
                                       const float4 k0, const float4 k1,
                                       const float4 k2, const float4 k3) {
  const float4 q0 = *reinterpret_cast<const float4*>(qrow);
  const float4 q1 = *reinterpret_cast<const float4*>(qrow + 32);
  const float4 q2 = *reinterpret_cast<const float4*>(qrow + 64);
  const float4 q3 = *reinterpret_cast<const float4*>(qrow + 96);
  float s;
  s = q0.x * k0.x;
  s = fmaf(q0.y, k0.y, s); s = fmaf(q0.z, k0.z, s); s = fmaf(q0.w, k0.w, s);
  s = fmaf(q1.x, k1.x, s); s = fmaf(q1.y, k1.y, s);
  s = fmaf(q1.z, k1.z, s); s = fmaf(q1.w, k1.w, s);
  s = fmaf(q2.x, k2.x, s); s = fmaf(q2.y, k2.y, s);
  s = fmaf(q2.z, k2.z, s); s = fmaf(q2.w, k2.w, s);
  s = fmaf(q3.x, k3.x, s); s = fmaf(q3.y, k3.y, s);
  s = fmaf(q3.z, k3.z, s); s = fmaf(q3.w, k3.w, s);
  return s;
}

// ---------------------------------------------------------------------------
// Kernel 3: p-split attention, register-disciplined. grid (NCH1, H_),
// block 512 = 8 waves = 4 row-groups x 2 m-halves. Each K/V row is loaded by
// exactly ONE wave. IDENTICAL to round 10 except __launch_bounds__(512, 2):
// min_waves=4 clamps the allocator to the 64-VGPR step and spills ~50
// regs/thread (3rd occurrence: r3, r5, r10). Demand ~110 VGPR lands in the
// <=128 band -> same 4 waves/SIMD at runtime, no spill.
// ---------------------------------------------------------------------------
__global__ __launch_bounds__(512, 2) void k_attn(const float* __restrict__ cacheK,
                                                 const float* __restrict__ cacheV,
                                                 const float* __restrict__ qkv,
                                                 float* __restrict__ opart,
                                                 float* __restrict__ ml) {
  const int c = blockIdx.x, h = blockIdx.y;
  const int t = threadIdx.x;
  const int wave = t >> 6, lane = t & 63;
  const int valid = (c < NCH) ? CHUNK : M_;
  const float* __restrict__ Ksrc = (c < NCH)
      ? (cacheK + ((size_t)h * P_ + (size_t)c * CHUNK) * D_)
      : (qkv + (size_t)((1 * H_ + h) * M_) * D_);
  const float* __restrict__ Vsrc = (c < NCH)
      ? (cacheV + ((size_t)h * P_ + (size_t)c * CHUNK) * D_)
      : (qkv + (size_t)((2 * H_ + h) * M_) * D_);

  __shared__ __align__(16) float smem[8192];     // 32 KB: qs[2048] + wx[1024] / obuf[8192]
  __shared__ __align__(16) float mlx[8][8][2];   // per-wave (m, l)

  float* qs = smem;                        // [16][128]
  float* wxp = smem + 2048 + wave * 128;   // wave-private [16 rows][8 m]

  // stage q (16x128) — the only barrier-producing stage before the merge
  {
    const float4* src = reinterpret_cast<const float4*>(qkv + (size_t)(h * M_) * D_);
    reinterpret_cast<float4*>(qs)[t] = src[t];
  }
  __syncthreads();

  const int pg = lane >> 3, dq = lane & 7;
  const int dl = lane * 2;
  const int rg = wave >> 1, mbase = (wave & 1) * 8;
  const int rbase = rg * 32;
  int rc = valid - rbase; rc = (rc < 0) ? 0 : ((rc > 32) ? 32 : rc);
  const int nb = rc >> 4;   // 16-row batches: 2, 1, or 0

  float mrun = -3.0e38f, lrun = 0.f;
  float2 o[8];
#pragma unroll
  for (int mi = 0; mi < 8; ++mi) o[mi] = make_float2(0.f, 0.f);

#pragma unroll 1
  for (int b = 0; b < nb; ++b) {
    const int r0 = rbase + b * 16;

    // ---- K loads for both 8-row halves, issued up-front ----
    float4 kA0, kA1, kA2, kA3, kB0, kB1, kB2, kB3;
    {
      const float* ka = Ksrc + (size_t)(r0 + pg) * D_ + dq * 4;
      kA0 = *reinterpret_cast<const float4*>(ka);
      kA1 = *reinterpret_cast<const float4*>(ka + 32);
      kA2 = *reinterpret_cast<const float4*>(ka + 64);
      kA3 = *reinterpret_cast<const float4*>(ka + 96);
      const float* kb = Ksrc + (size_t)(r0 + 8 + pg) * D_ + dq * 4;
      kB0 = *reinterpret_cast<const float4*>(kb);
      kB1 = *reinterpret_cast<const float4*>(kb + 32);
      kB2 = *reinterpret_cast<const float4*>(kb + 64);
      kB3 = *reinterpret_cast<const float4*>(kb + 96);
    }

    // ---- scores rows r0..r0+7 ----
    float a[8];
#pragma unroll
    for (int mi = 0; mi < 8; ++mi) {
      a[mi] = dot16(qs + (mbase + mi) * D_ + dq * 4, kA0, kA1, kA2, kA3);
      __builtin_amdgcn_sched_barrier(0);  // cap q ds_read clustering (r9 spill fix)
    }
    const float sA = fold8(a, dq);

    // ---- scores rows r0+8..r0+15 ----
#pragma unroll
    for (int mi = 0; mi < 8; ++mi) {
      a[mi] = dot16(qs + (mbase + mi) * D_ + dq * 4, kB0, kB1, kB2, kB3);
      __builtin_amdgcn_sched_barrier(0);
    }
    const float sB = fold8(a, dq);

    // ---- online softmax over the 16 rows (rows live across pg lanes) ----
    float tmax = fmaxf(sA, sB);
    tmax = fmaxf(tmax, __shfl_xor(tmax, 8));
    tmax = fmaxf(tmax, __shfl_xor(tmax, 16));
    tmax = fmaxf(tmax, __shfl_xor(tmax, 32));
    const float mnew = fmaxf(mrun, tmax);
    const float fc = __expf(mrun - mnew);
    mrun = mnew;
    const float wA = __expf(sA - mnew);
    const float wB = __expf(sB - mnew);
    float rs = wA + wB;
    rs += __shfl_xor(rs, 8); rs += __shfl_xor(rs, 16); rs += __shfl_xor(rs, 32);
    lrun = lrun * fc + rs;

    // publish weights (wave-private strip; same-wave RAW ordered by lgkmcnt)
    wxp[pg * 8 + dq] = wA;
    wxp[(8 + pg) * 8 + dq] = wB;

    // ---- rescale o by this batch's factor (per-m fc gathered via shfl) ----
#pragma unroll
    for (int mi = 0; mi < 8; ++mi) {
      const float fcm = __shfl(fc, (lane & 56) | mi);
      o[mi].x *= fcm; o[mi].y *= fcm;
    }

    // ---- V loads for all 16 rows, issued up-front ----
    float2 vvA[8], vvB[8];
#pragma unroll
    for (int j = 0; j < 8; ++j)
      vvA[j] = *reinterpret_cast<const float2*>(Vsrc + (size_t)(r0 + j) * D_ + dl);
#pragma unroll
    for (int j = 0; j < 8; ++j)
      vvB[j] = *reinterpret_cast<const float2*>(Vsrc + (size_t)(r0 + 8 + j) * D_ + dl);

    // ---- PV rows r0..r0+7 ----
#pragma unroll
    for (int j = 0; j < 8; ++j) {
      const float4 w0 = *reinterpret_cast<const float4*>(&wxp[j * 8]);
      const float4 w1 = *reinterpret_cast<const float4*>(&wxp[j * 8 + 4]);
      const float2 v = vvA[j];
#define PVM(i, wc) o[i].x = fmaf(wc, v.x, o[i].x); o[i].y = fmaf(wc, v.y, o[i].y);
      PVM(0, w0.x) PVM(1, w0.y) PVM(2, w0.z) PVM(3, w0.w)
      PVM(4, w1.x) PVM(5, w1.y) PVM(6, w1.z) PVM(7, w1.w)
#undef PVM
      if (j & 1) __builtin_amdgcn_sched_barrier(0);
    }
    // ---- PV rows r0+8..r0+15 ----
#pragma unroll
    for (int j = 0; j < 8; ++j) {
      const float4 w0 = *reinterpret_cast<const float4*>(&wxp[(8 + j) * 8]);
      const float4 w1 = *reinterpret_cast<const float4*>(&wxp[(8 + j) * 8 + 4]);
      const float2 v = vvB[j];
#define PVM(i, wc) o[i].x = fmaf(wc, v.x, o[i].x); o[i].y = fmaf(wc, v.y, o[i].y);
      PVM(0, w0.x) PVM(1, w0.y) PVM(2, w0.z) PVM(3, w0.w)
      PVM(4, w1.x) PVM(5, w1.y) PVM(6, w1.z) PVM(7, w1.w)
#undef PVM
      if (j & 1) __builtin_amdgcn_sched_barrier(0);
    }
  }

  // ---- merge the 8 wave-partials (obuf aliases dead qs/wx) ----
  __syncthreads();
  float* obuf = smem;  // [8 waves][8 m][128 d]
#pragma unroll
  for (int mi = 0; mi < 8; ++mi)
    *reinterpret_cast<float2*>(&obuf[wave * 1024 + mi * 128 + dl]) = o[mi];
  if (lane < 8) { mlx[wave][lane][0] = mrun; mlx[wave][lane][1] = lrun; }
  __syncthreads();

  {
    const int mm = t >> 5, seg = t & 31;    // 16 m x 32 segments of 4 d
    const int w0i = mm >> 3, mi = mm & 7;   // wave = rg*2 + w0i holds this m
    float mv[4], lv[4];
#pragma unroll
    for (int r = 0; r < 4; ++r) { mv[r] = mlx[r * 2 + w0i][mi][0]; lv[r] = mlx[r * 2 + w0i][mi][1]; }
    const float mstar = fmaxf(fmaxf(mv[0], mv[1]), fmaxf(mv[2], mv[3]));
    float ew[4];
    float T = 0.f;
#pragma unroll
    for (int r = 0; r < 4; ++r) { ew[r] = __expf(mv[r] - mstar); T = fmaf(lv[r], ew[r], T); }
    float4 acc = make_float4(0.f, 0.f, 0.f, 0.f);
#pragma unroll
    for (int r = 0; r < 4; ++r) {
      const float4 v = *reinterpret_cast<const float4*>(&obuf[(r * 2 + w0i) * 1024 + mi * 128 + seg * 4]);
      acc.x = fmaf(ew[r], v.x, acc.x); acc.y = fmaf(ew[r], v.y, acc.y);
      acc.z = fmaf(ew[r], v.z, acc.z); acc.w = fmaf(ew[r], v.w, acc.w);
    }
    const size_t base = (size_t)((h * NCH1 + c) * M_ + mm) * D_;
    *reinterpret_cast<float4*>(opart + base + seg * 4) = acc;
    if (seg == 0) {
      ml[((size_t)(h * NCH1 + c) * M_ + mm) * 2 + 0] = mstar;
      ml[((size_t)(h * NCH1 + c) * M_ + mm) * 2 + 1] = T;
    }
  }
}

// ---------------------------------------------------------------------------
// Kernel 4: combine 65 chunk partials per (h, m). grid (M_, H_), block 128.
// ---------------------------------------------------------------------------
__global__ __launch_bounds__(128) void k_comb(const float* __restrict__ opart,
                                              const float* __restrict__ ml,
                                              float* __restrict__ out) {
  const int m = blockIdx.x, h = blockIdx.y, t = threadIdx.x;
  __shared__ float Ms[NCH1], Ls[NCH1];
  if (t < NCH1) {
    Ms[t] = ml[((size_t)(h * NCH1 + t) * M_ + m) * 2 + 0];
    Ls[t] = ml[((size_t)(h * NCH1 + t) * M_ + m) * 2 + 1];
  }
  __syncthreads();
  float gM = -3.0e38f;
#pragma unroll
  for (int c2 = 0; c2 < NCH1; ++c2) gM = fmaxf(gM, Ms[c2]);

  const float* __restrict__ ob = opart + (size_t)h * NCH1 * M_ * D_ + (size_t)m * D_ + t;
  float T = 0.f, o0 = 0.f, o1 = 0.f, o2 = 0.f, o3 = 0.f;
#pragma unroll 4
  for (int c2 = 0; c2 < NCH1 - 1; c2 += 4) {
    const float f0 = __expf(Ms[c2 + 0] - gM);
    const float f1 = __expf(Ms[c2 + 1] - gM);
    const float f2 = __expf(Ms[c2 + 2] - gM);
    const float f3 = __expf(Ms[c2 + 3] - gM);
    T = fmaf(Ls[c2 + 0], f0, T); T = fmaf(Ls[c2 + 1], f1, T);
    T = fmaf(Ls[c2 + 2], f2, T); T = fmaf(Ls[c2 + 3], f3, T);
    o0 = fmaf(ob[(size_t)(c2 + 0) * M_ * D_], f0, o0);
    o1 = fmaf(ob[(size_t)(c2 + 1) * M_ * D_], f1, o1);
    o2 = fmaf(ob[(size_t)(c2 + 2) * M_ * D_], f2, o2);
    o3 = fmaf(ob[(size_t)(c2 + 3) * M_ * D_], f3, o3);
  }
  {
    const int c2 = NCH1 - 1;
    const float f = __expf(Ms[c2] - gM);
    T = fmaf(Ls[c2], f, T);
    o0 = fmaf(ob[(size_t)c2 * M_ * D_], f, o0);
  }
  out[(size_t)m * N_ + h * D_ + t] = (o0 + o1 + o2 + o3) / T;
}

// ---------------------------------------------------------------------------
extern "C" void kernel_launch(void* const* d_in, const int* in_sizes, int n_in,
                              void* d_out, int out_size, void* d_ws, size_t ws_size,
                              hipStream_t stream) {
  const float* X  = (const float*)d_in[0];
  const float* Wq = (const float*)d_in[1];
  const float* Wk = (const float*)d_in[2];
  const float* Wv = (const float*)d_in[3];
  const float* cK = (const float*)d_in[4];
  const float* cV = (const float*)d_in[5];
  float* ws    = (float*)d_ws;
  float* qkv   = ws;
  float* part  = ws + PART_OFF;
  float* opart = ws + OPART_OFF;
  float* mlbuf = ws + ML_OFF;
  float* out   = (float*)d_out;

  hipLaunchKernelGGL(k_proj,   dim3(NCB, NIC, 3), dim3(256), 0, stream, X, Wq, Wk, Wv, part);
  hipLaunchKernelGGL(k_reduce, dim3(16, M_, 3),   dim3(256), 0, stream, part, qkv);
  hipLaunchKernelGGL(k_attn,   dim3(NCH1, H_),    dim3(512), 0, stream, cK, cV, qkv, opart, mlbuf);
  hipLaunchKernelGGL(k_comb,   dim3(M_, H_),      dim3(128), 0, stream, opart, mlbuf, out);
}